// Round 6
// baseline (297.363 us; speedup 1.0000x reference)
//
#include <hip/hip_runtime.h>

// TinyDLRM v5: out[i] = sigmoid( relu( f @ w1 + b1 ) @ w2 + b2 )
//
// Evidence v1-v4: time == (FETCH+WRITE)/3.5-3.6 TB/s across four kernels ->
// random-64B-sector L2-fill bandwidth ceiling. Effective cache = 4 MB per-XCD
// L2 (not 32 MB aggregate): fp16 repack (32 MB working set) only cut fetch
// 540->510 MB. Reorder pipelines don't pay (sort streaming + out-scatter
// write amplification >= random-gather savings); fp8 fails the error budget.
//
// v5 = v4 + nontemporal hints on the ~100 MB of touch-once streams
// (ids/dense/out) so they stop churning table lines out of the 4 MB L2s.
// Gathers (user/item fp16, cat fp32) keep caching semantics.

#define HIDDEN 16
#define IN_DIM 26

typedef _Float16 hv8 __attribute__((ext_vector_type(8)));
typedef float    fv2 __attribute__((ext_vector_type(2)));

// ---------------- repack: fp32 [rows,8] -> fp16 [rows,8] ----------------
__global__ __launch_bounds__(256) void repack_kernel(
    const float* __restrict__ user_table,
    const float* __restrict__ item_table,
    _Float16*    __restrict__ user_h,
    _Float16*    __restrict__ item_h,
    int rows_per_table)
{
    int i = blockIdx.x * blockDim.x + threadIdx.x;
    const float* src;
    _Float16* dst;
    int r;
    if (i < rows_per_table) {
        src = user_table; dst = user_h; r = i;
    } else if (i < 2 * rows_per_table) {
        src = item_table; dst = item_h; r = i - rows_per_table;
    } else {
        return;
    }
    float4 a = ((const float4*)src)[2 * r];
    float4 b = ((const float4*)src)[2 * r + 1];
    hv8 h = {(_Float16)a.x, (_Float16)a.y, (_Float16)a.z, (_Float16)a.w,
             (_Float16)b.x, (_Float16)b.y, (_Float16)b.z, (_Float16)b.w};
    ((hv8*)dst)[r] = h;
}

// ---------------- main kernel, fp16 user/item tables ----------------
__global__ __launch_bounds__(256) void tiny_dlrm_h_kernel(
    const int*      __restrict__ user_id,
    const int*      __restrict__ item_id,
    const int*      __restrict__ cat_id,
    const float*    __restrict__ dense,      // [B,2]
    const _Float16* __restrict__ user_h,     // [NU,8] fp16
    const _Float16* __restrict__ item_h,     // [NI,8] fp16
    const float*    __restrict__ cat_table,  // [NC,8] fp32
    const float*    __restrict__ w1,         // [26,16]
    const float*    __restrict__ b1,
    const float*    __restrict__ w2,
    const float*    __restrict__ b2,
    float*          __restrict__ out,
    int batch)
{
    int i = blockIdx.x * blockDim.x + threadIdx.x;
    if (i >= batch) return;

    // touch-once streams: nontemporal (evict-first) to protect table lines in L2
    int u = __builtin_nontemporal_load(user_id + i);
    int v = __builtin_nontemporal_load(item_id + i);
    int c = __builtin_nontemporal_load(cat_id + i);
    fv2 dd = __builtin_nontemporal_load((const fv2*)dense + i);

    // gathers: caching semantics (these are the reused bytes)
    hv8 ur = ((const hv8*)user_h)[u];                       // 16 B, one line
    hv8 ir = ((const hv8*)item_h)[v];                       // 16 B, one line
    const float4* cp = (const float4*)(cat_table + (size_t)c * 8);
    float4 c0 = cp[0], c1 = cp[1];                          // L2-resident

    float f[IN_DIM] = {
        (float)ur[0], (float)ur[1], (float)ur[2], (float)ur[3],
        (float)ur[4], (float)ur[5], (float)ur[6], (float)ur[7],
        (float)ir[0], (float)ir[1], (float)ir[2], (float)ir[3],
        (float)ir[4], (float)ir[5], (float)ir[6], (float)ir[7],
        c0.x, c0.y, c0.z, c0.w, c1.x, c1.y, c1.z, c1.w,
        dd.x, dd.y
    };

    float h[HIDDEN];
#pragma unroll
    for (int j = 0; j < HIDDEN; ++j) h[j] = b1[j];
#pragma unroll
    for (int k = 0; k < IN_DIM; ++k) {
        float fk = f[k];
#pragma unroll
        for (int j = 0; j < HIDDEN; ++j)
            h[j] = fmaf(fk, w1[k * HIDDEN + j], h[j]);
    }
    float acc = b2[0];
#pragma unroll
    for (int j = 0; j < HIDDEN; ++j)
        acc = fmaf(fmaxf(h[j], 0.0f), w2[j], acc);

    float o = 1.0f / (1.0f + __expf(-acc));
    __builtin_nontemporal_store(o, out + i);
}

// ---------------- fallback: proven v1 fp32 kernel ----------------
__global__ __launch_bounds__(256) void tiny_dlrm_kernel(
    const int*   __restrict__ user_id,
    const int*   __restrict__ item_id,
    const int*   __restrict__ cat_id,
    const float* __restrict__ dense,
    const float* __restrict__ user_table,
    const float* __restrict__ item_table,
    const float* __restrict__ cat_table,
    const float* __restrict__ w1,
    const float* __restrict__ b1,
    const float* __restrict__ w2,
    const float* __restrict__ b2,
    float*       __restrict__ out,
    int batch)
{
    int i = blockIdx.x * blockDim.x + threadIdx.x;
    if (i >= batch) return;

    int u = user_id[i];
    int v = item_id[i];
    int c = cat_id[i];

    const float4* up = (const float4*)(user_table + (size_t)u * 8);
    const float4* ip = (const float4*)(item_table + (size_t)v * 8);
    const float4* cp = (const float4*)(cat_table  + (size_t)c * 8);
    float4 u0 = up[0], u1 = up[1];
    float4 i0 = ip[0], i1 = ip[1];
    float4 c0 = cp[0], c1 = cp[1];
    float2 dd = ((const float2*)dense)[i];

    float f[IN_DIM] = {
        u0.x, u0.y, u0.z, u0.w, u1.x, u1.y, u1.z, u1.w,
        i0.x, i0.y, i0.z, i0.w, i1.x, i1.y, i1.z, i1.w,
        c0.x, c0.y, c0.z, c0.w, c1.x, c1.y, c1.z, c1.w,
        dd.x, dd.y
    };

    float h[HIDDEN];
#pragma unroll
    for (int j = 0; j < HIDDEN; ++j) h[j] = b1[j];
#pragma unroll
    for (int k = 0; k < IN_DIM; ++k) {
        float fk = f[k];
#pragma unroll
        for (int j = 0; j < HIDDEN; ++j)
            h[j] = fmaf(fk, w1[k * HIDDEN + j], h[j]);
    }
    float acc = b2[0];
#pragma unroll
    for (int j = 0; j < HIDDEN; ++j)
        acc = fmaf(fmaxf(h[j], 0.0f), w2[j], acc);

    out[i] = 1.0f / (1.0f + __expf(-acc));
}

extern "C" void kernel_launch(void* const* d_in, const int* in_sizes, int n_in,
                              void* d_out, int out_size, void* d_ws, size_t ws_size,
                              hipStream_t stream) {
    const int*   user_id    = (const int*)d_in[0];
    const int*   item_id    = (const int*)d_in[1];
    const int*   cat_id     = (const int*)d_in[2];
    const float* dense      = (const float*)d_in[3];
    const float* user_table = (const float*)d_in[4];
    const float* item_table = (const float*)d_in[5];
    const float* cat_table  = (const float*)d_in[6];
    const float* w1         = (const float*)d_in[7];
    const float* b1         = (const float*)d_in[8];
    const float* w2         = (const float*)d_in[9];
    const float* b2         = (const float*)d_in[10];
    float* out = (float*)d_out;

    int batch = in_sizes[0];
    int user_rows = in_sizes[4] / 8;   // 1,000,000
    int item_rows = in_sizes[5] / 8;   // 1,000,000

    size_t user_bytes = (size_t)user_rows * 8 * sizeof(_Float16);
    size_t need = user_bytes + (size_t)item_rows * 8 * sizeof(_Float16);

    int block = 256;
    int grid = (batch + block - 1) / block;

    if (ws_size >= need && user_rows == item_rows) {
        _Float16* user_h = (_Float16*)d_ws;
        _Float16* item_h = (_Float16*)((char*)d_ws + user_bytes);

        int rp_threads = 2 * user_rows;
        int rp_grid = (rp_threads + block - 1) / block;
        repack_kernel<<<rp_grid, block, 0, stream>>>(
            user_table, item_table, user_h, item_h, user_rows);

        tiny_dlrm_h_kernel<<<grid, block, 0, stream>>>(
            user_id, item_id, cat_id, dense,
            user_h, item_h, cat_table,
            w1, b1, w2, b2, out, batch);
    } else {
        tiny_dlrm_kernel<<<grid, block, 0, stream>>>(
            user_id, item_id, cat_id, dense,
            user_table, item_table, cat_table,
            w1, b1, w2, b2, out, batch);
    }
}